// Round 4
// baseline (171.292 us; speedup 1.0000x reference)
//
#include <hip/hip_runtime.h>
#include <math.h>

// Shapes (from setup_inputs): B=2, N=512, C=256, H=128, W=224.
#define MAXN 1024
#define PTS 8   // points per MLP block
#define CG 16   // channels per splat block (4 waves x 4 channels)

// ---------------- kernel 1: per-gaussian projection/prep ----------------
__global__ void prep_kernel(const float* __restrict__ gd,
                            const float* __restrict__ Kmat,
                            float4* __restrict__ bbox,
                            float4* __restrict__ prm,
                            int N, int B, float Wf, float Hf) {
  int i = blockIdx.x * blockDim.x + threadIdx.x;
  if (i >= B * N) return;
  int b = i / N;
  const float* g = gd + (size_t)i * 14;
  float X = g[0], Y = g[1], Z = g[2];
  float sigx = g[5], sigy = g[6], wt = g[12];
  const float* K = Kmat + (size_t)b * 9;
  float p0 = K[0]*X + K[1]*Y + K[2]*Z;
  float p1 = K[3]*X + K[4]*Y + K[5]*Z;
  float p2 = K[6]*X + K[7]*Y + K[8]*Z;
  float denom = p2 + 1e-6f;
  float p2x = p0 / denom, p2y = p1 / denom;
  float scale_x = Wf / K[2] * 0.5f;   // W / K[0,2] / 2
  float scale_y = Hf / K[5] * 0.5f;   // H / K[1,2] / 2
  float cx = p2x * scale_x;
  float cy = p2y * scale_y;
  bool valid = Z > 0.1f;
  bool inb = (cx >= 0.f) && (cx < Wf) && (cy >= 0.f) && (cy < Hf);
  bool active = valid && inb;
  float sxv = fmaxf(sigx * scale_x, 1.f);
  float syv = fmaxf(sigy * scale_y, 1.f);
  float wn = active ? wt : 0.f;
  float avg = 0.5f * (sxv + syv);
  if (active && wn != 0.f) {
    bbox[i] = make_float4(cx, cy, 3.f * sxv, 3.f * syv);
  } else {
    bbox[i] = make_float4(-1e30f, -1e30f, 0.f, 0.f);  // never culled-in
  }
  prm[i] = make_float4(1.f / sxv, 1.f / syv, wn, avg);
}

// ---------------- kernel 2: MLP h = relu(pf@W1^T+b1)@W2^T+b2 ----------------
// 8 points per block: W1/W2 L2 traffic amortized 8x; x reads are LDS broadcasts.
__global__ __launch_bounds__(256, 2) void mlp_kernel(
    const float* __restrict__ pf, const float* __restrict__ W1,
    const float* __restrict__ b1, const float* __restrict__ W2,
    const float* __restrict__ b2, float* __restrict__ hout, int npts) {
  const int t = threadIdx.x;            // output channel (C==256)
  const int p0 = blockIdx.x * PTS;
  __shared__ __align__(16) float xs[PTS][256];

  const float4* pf4 = (const float4*)(pf + (size_t)p0 * 256);
  float4* xs4 = (float4*)&xs[0][0];
  #pragma unroll
  for (int i = 0; i < PTS * 64 / 256; ++i) xs4[t + 256 * i] = pf4[t + 256 * i];
  __syncthreads();

  float acc[PTS];
  float bb1 = b1[t];
  #pragma unroll
  for (int p = 0; p < PTS; ++p) acc[p] = bb1;
  const float* w1r = W1 + (size_t)t * 256;
  for (int k = 0; k < 256; k += 4) {
    float4 w = *(const float4*)(w1r + k);
    #pragma unroll
    for (int p = 0; p < PTS; ++p) {
      float4 x = *(const float4*)(&xs[p][k]);
      acc[p] += w.x * x.x + w.y * x.y + w.z * x.z + w.w * x.w;
    }
  }
  __syncthreads();
  #pragma unroll
  for (int p = 0; p < PTS; ++p) xs[p][t] = fmaxf(acc[p], 0.f);
  __syncthreads();

  float acc2[PTS];
  float bb2 = b2[t];
  #pragma unroll
  for (int p = 0; p < PTS; ++p) acc2[p] = bb2;
  const float* w2r = W2 + (size_t)t * 256;
  for (int k = 0; k < 256; k += 4) {
    float4 w = *(const float4*)(w2r + k);
    #pragma unroll
    for (int p = 0; p < PTS; ++p) {
      float4 x = *(const float4*)(&xs[p][k]);
      acc2[p] += w.x * x.x + w.y * x.y + w.z * x.z + w.w * x.w;
    }
  }
  #pragma unroll
  for (int p = 0; p < PTS; ++p)
    if (p0 + p < npts) hout[((size_t)(p0 + p)) * 256 + t] = acc2[p];
}

// ---------------- kernel 3: gather-splat, lanes along x ----------------
// block = (channel-group of CG=16, row, b); 256 threads.
// wave cs = t>>6 owns channels c0+4*cs .. +3 ; lane xq = t&63 owns pixels
// 4*xq .. 4*xq+3 (active for xq<56 since W=224). Stores: one float4 per
// (channel,row) = 56 lanes x 16B = 896B CONTIGUOUS per wave-store — vs the
// old thread=channel layout whose stores scattered 64 lanes across 64
// distinct 114KB-strided lines (the 124us bottleneck, rounds 1-3).
__global__ __launch_bounds__(256) void splat_kernel(
    const float4* __restrict__ bbox, const float4* __restrict__ prm,
    const float* __restrict__ hfeat, float* __restrict__ fout,
    float* __restrict__ unc_out, float* __restrict__ dens_out,
    int N, int C, int H, int W) {
  const int t = threadIdx.x;
  const int b = blockIdx.z;
  const int row = blockIdx.y;
  const int c0 = blockIdx.x * CG;
  const int HW = H * W;
  const int xq = t & 63;     // lane: x-quad
  const int cs = t >> 6;     // wave: channel sub-group

  __shared__ int glist[MAXN];
  __shared__ int wcnt[4];

  const float rf = (float)row;
  const float wmax = (float)(W - 1);
  const int lane = t & 63, wave = t >> 6;
  const unsigned long long lmask = (1ull << lane) - 1ull;
  const size_t bN = (size_t)b * N;

  // ---- deterministic ordered cull for this row (ballot + cross-wave prefix) ----
  int listlen = 0;
  for (int gb = 0; gb < N; gb += 256) {
    int g = gb + t;
    bool f = false;
    if (g < N) {
      float4 bb = bbox[bN + g];
      f = (bb.y - bb.w <= rf) && (bb.y + bb.w >= rf) &&
          (bb.x + bb.z >= 0.f) && (bb.x - bb.z <= wmax);
    }
    unsigned long long m = __ballot(f);
    if (lane == 0) wcnt[wave] = __popcll(m);
    __syncthreads();
    int pre = 0;
    #pragma unroll
    for (int wv = 0; wv < 4; ++wv) pre += (wv < wave) ? wcnt[wv] : 0;
    int tot = wcnt[0] + wcnt[1] + wcnt[2] + wcnt[3];
    if (f) glist[listlen + pre + __popcll(m & lmask)] = g;
    __syncthreads();
    listlen += tot;
  }

  // ---- accumulate: 16 named channel-x-px accs + density/uncertainty ----
  float a00=0.f,a01=0.f,a02=0.f,a03=0.f;   // channel c0+4cs+0, px j=0..3
  float a10=0.f,a11=0.f,a12=0.f,a13=0.f;   // +1
  float a20=0.f,a21=0.f,a22=0.f,a23=0.f;   // +2
  float a30=0.f,a31=0.f,a32=0.f,a33=0.f;   // +3
  float d0=0.f,d1=0.f,d2=0.f,d3=0.f;
  float u0=0.f,u1=0.f,u2=0.f,u3=0.f;
  const float xf = (float)(4 * xq);

  for (int gi = 0; gi < listlen; ++gi) {
    int g = glist[gi];
    float4 bb = bbox[bN + g];
    float4 pr = prm[bN + g];
    float4 hv = *(const float4*)(hfeat + ((size_t)bN + g) * C + c0 + 4 * cs);
    float dy = (rf - bb.y) * pr.y;
    float dy2 = dy * dy;

    float dx0 = (xf + 0.f - bb.x) * pr.x; float q0 = dx0*dx0 + dy2;
    float dx1 = (xf + 1.f - bb.x) * pr.x; float q1 = dx1*dx1 + dy2;
    float dx2 = (xf + 2.f - bb.x) * pr.x; float q2 = dx2*dx2 + dy2;
    float dx3 = (xf + 3.f - bb.x) * pr.x; float q3 = dx3*dx3 + dy2;
    float w0 = (q0 < 9.f) ? __expf(-0.5f * q0) * pr.z : 0.f;
    float w1 = (q1 < 9.f) ? __expf(-0.5f * q1) * pr.z : 0.f;
    float w2 = (q2 < 9.f) ? __expf(-0.5f * q2) * pr.z : 0.f;
    float w3 = (q3 < 9.f) ? __expf(-0.5f * q3) * pr.z : 0.f;

    d0 += w0; d1 += w1; d2 += w2; d3 += w3;
    u0 += w0 * pr.w; u1 += w1 * pr.w; u2 += w2 * pr.w; u3 += w3 * pr.w;

    a00 += w0 * hv.x; a01 += w1 * hv.x; a02 += w2 * hv.x; a03 += w3 * hv.x;
    a10 += w0 * hv.y; a11 += w1 * hv.y; a12 += w2 * hv.y; a13 += w3 * hv.y;
    a20 += w0 * hv.z; a21 += w1 * hv.z; a22 += w2 * hv.z; a23 += w3 * hv.z;
    a30 += w0 * hv.w; a31 += w1 * hv.w; a32 += w2 * hv.w; a33 += w3 * hv.w;
  }

  // ---- normalize + coalesced write ----
  if (4 * xq < W) {
    float dc0 = fmaxf(d0, 1e-6f), dc1 = fmaxf(d1, 1e-6f);
    float dc2 = fmaxf(d2, 1e-6f), dc3 = fmaxf(d3, 1e-6f);
    float i0 = 1.f / dc0, i1 = 1.f / dc1, i2 = 1.f / dc2, i3 = 1.f / dc3;

    size_t rbase = (size_t)row * W + 4 * xq;
    float* f0 = fout + ((size_t)(b * C + c0 + 4 * cs)) * HW + rbase;
    *(float4*)(f0)           = make_float4(a00*i0, a01*i1, a02*i2, a03*i3);
    *(float4*)(f0 + HW)      = make_float4(a10*i0, a11*i1, a12*i2, a13*i3);
    *(float4*)(f0 + 2 * HW)  = make_float4(a20*i0, a21*i1, a22*i2, a23*i3);
    *(float4*)(f0 + 3 * HW)  = make_float4(a30*i0, a31*i1, a32*i2, a33*i3);

    if (c0 == 0 && cs == 0) {
      *(float4*)(dens_out + (size_t)b * HW + rbase) = make_float4(dc0, dc1, dc2, dc3);
      *(float4*)(unc_out  + (size_t)b * HW + rbase) = make_float4(u0*i0, u1*i1, u2*i2, u3*i3);
    }
  }
}

extern "C" void kernel_launch(void* const* d_in, const int* in_sizes, int n_in,
                              void* d_out, int out_size, void* d_ws, size_t ws_size,
                              hipStream_t stream) {
  const float* pf = (const float*)d_in[0];
  const float* gd = (const float*)d_in[1];
  const float* K  = (const float*)d_in[2];
  const float* W1 = (const float*)d_in[3];
  const float* b1 = (const float*)d_in[4];
  const float* W2 = (const float*)d_in[5];
  const float* b2 = (const float*)d_in[6];

  const int B = in_sizes[2] / 9;
  const int N = in_sizes[1] / (B * 14);
  const int C = in_sizes[0] / (B * N);
  const int H = 128, W = 224;

  float4* bbox = (float4*)d_ws;
  float4* prm  = bbox + (size_t)B * N;
  float*  hfe  = (float*)(prm + (size_t)B * N);

  float* out      = (float*)d_out;
  float* unc_out  = out + (size_t)B * C * H * W;
  float* dens_out = unc_out + (size_t)B * H * W;

  prep_kernel<<<dim3((B * N + 255) / 256), 256, 0, stream>>>(
      gd, K, bbox, prm, N, B, (float)W, (float)H);
  mlp_kernel<<<dim3((B * N + PTS - 1) / PTS), 256, 0, stream>>>(
      pf, W1, b1, W2, b2, hfe, B * N);
  splat_kernel<<<dim3(C / CG, H, B), 256, 0, stream>>>(
      bbox, prm, hfe, out, unc_out, dens_out, N, C, H, W);
}

// Round 5
// 105.747 us; speedup vs baseline: 1.6198x; 1.6198x over previous
//
#include <hip/hip_runtime.h>
#include <math.h>

// Shapes (from setup_inputs): B=2, N=512, C=256, H=128, W=224.
#define MAXN 1024
#define PTS 4   // points per MLP block (256 blocks -> 1 per CU)
#define PX 8    // pixels per splat block (28 x-tiles per row)

// ---------------- kernel 1: per-gaussian projection/prep ----------------
__global__ void prep_kernel(const float* __restrict__ gd,
                            const float* __restrict__ Kmat,
                            float4* __restrict__ bbox,
                            float4* __restrict__ prm,
                            int N, int B, float Wf, float Hf) {
  int i = blockIdx.x * blockDim.x + threadIdx.x;
  if (i >= B * N) return;
  int b = i / N;
  const float* g = gd + (size_t)i * 14;
  float X = g[0], Y = g[1], Z = g[2];
  float sigx = g[5], sigy = g[6], wt = g[12];
  const float* K = Kmat + (size_t)b * 9;
  float p0 = K[0]*X + K[1]*Y + K[2]*Z;
  float p1 = K[3]*X + K[4]*Y + K[5]*Z;
  float p2 = K[6]*X + K[7]*Y + K[8]*Z;
  float denom = p2 + 1e-6f;
  float p2x = p0 / denom, p2y = p1 / denom;
  float scale_x = Wf / K[2] * 0.5f;   // W / K[0,2] / 2
  float scale_y = Hf / K[5] * 0.5f;   // H / K[1,2] / 2
  float cx = p2x * scale_x;
  float cy = p2y * scale_y;
  bool valid = Z > 0.1f;
  bool inb = (cx >= 0.f) && (cx < Wf) && (cy >= 0.f) && (cy < Hf);
  bool active = valid && inb;
  float sxv = fmaxf(sigx * scale_x, 1.f);
  float syv = fmaxf(sigy * scale_y, 1.f);
  float wn = active ? wt : 0.f;
  float avg = 0.5f * (sxv + syv);
  if (active && wn != 0.f) {
    bbox[i] = make_float4(cx, cy, 3.f * sxv, 3.f * syv);
  } else {
    bbox[i] = make_float4(-1e30f, -1e30f, 0.f, 0.f);  // never culled-in
  }
  prm[i] = make_float4(1.f / sxv, 1.f / syv, wn, avg);
}

// ---------------- kernel 2: MLP h = relu(pf@W1^T+b1)@W2^T+b2 ----------------
// PTS=4 points/block -> 256 blocks (1/CU); W1/W2 stream from L2.
__global__ __launch_bounds__(256) void mlp_kernel(
    const float* __restrict__ pf, const float* __restrict__ W1,
    const float* __restrict__ b1, const float* __restrict__ W2,
    const float* __restrict__ b2, float* __restrict__ hout, int npts) {
  const int t = threadIdx.x;            // output channel (C==256)
  const int p0 = blockIdx.x * PTS;
  __shared__ __align__(16) float xs[PTS][256];

  const float4* pf4 = (const float4*)(pf + (size_t)p0 * 256);
  float4* xs4 = (float4*)&xs[0][0];
  #pragma unroll
  for (int i = 0; i < PTS * 64 / 256; ++i) xs4[t + 256 * i] = pf4[t + 256 * i];
  __syncthreads();

  float acc[PTS];
  float bb1 = b1[t];
  #pragma unroll
  for (int p = 0; p < PTS; ++p) acc[p] = bb1;
  const float* w1r = W1 + (size_t)t * 256;
  for (int k = 0; k < 256; k += 4) {
    float4 w = *(const float4*)(w1r + k);
    #pragma unroll
    for (int p = 0; p < PTS; ++p) {
      float4 x = *(const float4*)(&xs[p][k]);
      acc[p] += w.x * x.x + w.y * x.y + w.z * x.z + w.w * x.w;
    }
  }
  __syncthreads();
  #pragma unroll
  for (int p = 0; p < PTS; ++p) xs[p][t] = fmaxf(acc[p], 0.f);
  __syncthreads();

  float acc2[PTS];
  float bb2 = b2[t];
  #pragma unroll
  for (int p = 0; p < PTS; ++p) acc2[p] = bb2;
  const float* w2r = W2 + (size_t)t * 256;
  for (int k = 0; k < 256; k += 4) {
    float4 w = *(const float4*)(w2r + k);
    #pragma unroll
    for (int p = 0; p < PTS; ++p) {
      float4 x = *(const float4*)(&xs[p][k]);
      acc2[p] += w.x * x.x + w.y * x.y + w.z * x.z + w.w * x.w;
    }
  }
  #pragma unroll
  for (int p = 0; p < PTS; ++p)
    if (p0 + p < npts) hout[((size_t)(p0 + p)) * 256 + t] = acc2[p];
}

// ---------------- kernel 3: gather-splat, 8-px tile per block ----------------
// block = (x-tile of 8 px, row, b); 256 threads. x-tight cull -> per-tile
// gaussian count ~5-25 even on hot rows; weights computed once per block
// (no channel-group redundancy, unlike round 4's 16x). Phase B: thread =
// channel, only 8 accumulators/thread, zero barriers in the main loop.
__global__ __launch_bounds__(256) void splat_kernel(
    const float4* __restrict__ bbox, const float4* __restrict__ prm,
    const float* __restrict__ hfeat, float* __restrict__ fout,
    float* __restrict__ unc_out, float* __restrict__ dens_out,
    int N, int C, int H, int W) {
  const int t = threadIdx.x;
  const int b = blockIdx.z;
  const int row = blockIdx.y;
  const int x0 = blockIdx.x * PX;
  const int HW = H * W;

  __shared__ int glist[MAXN];
  __shared__ int wcnt[4];
  __shared__ __align__(16) float invd_s[PX];

  const float rf = (float)row;
  const float xlo = (float)x0, xhi = (float)(x0 + PX - 1);
  const int lane = t & 63, wave = t >> 6;
  const unsigned long long lmask = (1ull << lane) - 1ull;
  const size_t bN = (size_t)b * N;

  // ---- deterministic ordered cull (ballot + cross-wave prefix), x-tight ----
  int listlen = 0;
  for (int gb = 0; gb < N; gb += 256) {
    int g = gb + t;
    bool f = false;
    if (g < N) {
      float4 bb = bbox[bN + g];
      f = (bb.y - bb.w <= rf) && (bb.y + bb.w >= rf) &&
          (bb.x + bb.z >= xlo) && (bb.x - bb.z <= xhi);
    }
    unsigned long long m = __ballot(f);
    if (lane == 0) wcnt[wave] = __popcll(m);
    __syncthreads();
    int pre = 0;
    #pragma unroll
    for (int wv = 0; wv < 4; ++wv) pre += (wv < wave) ? wcnt[wv] : 0;
    int tot = wcnt[0] + wcnt[1] + wcnt[2] + wcnt[3];
    if (f) glist[listlen + pre + __popcll(m & lmask)] = g;
    __syncthreads();
    listlen += tot;
  }

  // ---- phase A: dens/unc for the 8 px (threads 0..7, glist order) ----
  // x-culled list is exact: excluded gaussians have q>9 -> w==0 contribution.
  if (t < PX) {
    const float pxf = (float)(x0 + t);
    float d = 0.f, u = 0.f;
    for (int gi = 0; gi < listlen; ++gi) {
      int g = glist[gi];
      float4 bb = bbox[bN + g];
      float4 pr = prm[bN + g];
      float dx = (pxf - bb.x) * pr.x;
      float dy = (rf - bb.y) * pr.y;
      float q = dx * dx + dy * dy;
      float w = (q < 9.f) ? __expf(-0.5f * q) * pr.z : 0.f;
      d += w; u += w * pr.w;
    }
    float dc = fmaxf(d, 1e-6f);
    float inv = 1.f / dc;
    invd_s[t] = inv;
    size_t pix = (size_t)b * HW + (size_t)row * W + x0 + t;
    dens_out[pix] = dc;
    unc_out[pix] = u * inv;
  }
  __syncthreads();

  // ---- phase B: thread = channel, 8 px accumulators ----
  float acc[PX];
  #pragma unroll
  for (int j = 0; j < PX; ++j) acc[j] = 0.f;
  const float xf = (float)x0;

  for (int gi = 0; gi < listlen; ++gi) {
    int g = glist[gi];
    float4 bb = bbox[bN + g];
    float4 pr = prm[bN + g];
    float hv = hfeat[(bN + g) * (size_t)C + t];
    float dy = (rf - bb.y) * pr.y;
    float dy2 = dy * dy;
    #pragma unroll
    for (int j = 0; j < PX; ++j) {
      float dx = (xf + (float)j - bb.x) * pr.x;
      float q = dx * dx + dy2;
      float w = (q < 9.f) ? __expf(-0.5f * q) * pr.z : 0.f;
      acc[j] += w * hv;
    }
  }

  // ---- normalize + write: 2 float4 per thread ----
  float* fo = fout + ((size_t)(b * C + t)) * HW + (size_t)row * W + x0;
  float4 lo = make_float4(acc[0] * invd_s[0], acc[1] * invd_s[1],
                          acc[2] * invd_s[2], acc[3] * invd_s[3]);
  float4 hi = make_float4(acc[4] * invd_s[4], acc[5] * invd_s[5],
                          acc[6] * invd_s[6], acc[7] * invd_s[7]);
  *(float4*)(fo) = lo;
  *(float4*)(fo + 4) = hi;
}

extern "C" void kernel_launch(void* const* d_in, const int* in_sizes, int n_in,
                              void* d_out, int out_size, void* d_ws, size_t ws_size,
                              hipStream_t stream) {
  const float* pf = (const float*)d_in[0];
  const float* gd = (const float*)d_in[1];
  const float* K  = (const float*)d_in[2];
  const float* W1 = (const float*)d_in[3];
  const float* b1 = (const float*)d_in[4];
  const float* W2 = (const float*)d_in[5];
  const float* b2 = (const float*)d_in[6];

  const int B = in_sizes[2] / 9;
  const int N = in_sizes[1] / (B * 14);
  const int C = in_sizes[0] / (B * N);
  const int H = 128, W = 224;

  float4* bbox = (float4*)d_ws;
  float4* prm  = bbox + (size_t)B * N;
  float*  hfe  = (float*)(prm + (size_t)B * N);

  float* out      = (float*)d_out;
  float* unc_out  = out + (size_t)B * C * H * W;
  float* dens_out = unc_out + (size_t)B * H * W;

  prep_kernel<<<dim3((B * N + 255) / 256), 256, 0, stream>>>(
      gd, K, bbox, prm, N, B, (float)W, (float)H);
  mlp_kernel<<<dim3((B * N + PTS - 1) / PTS), 256, 0, stream>>>(
      pf, W1, b1, W2, b2, hfe, B * N);
  splat_kernel<<<dim3(W / PX, H, B), 256, 0, stream>>>(
      bbox, prm, hfe, out, unc_out, dens_out, N, C, H, W);
}

// Round 6
// 83.066 us; speedup vs baseline: 2.0621x; 1.2730x over previous
//
#include <hip/hip_runtime.h>
#include <math.h>

// Shapes (from setup_inputs): B=2, N=512, C=256, H=128, W=224.
#define MAXN 1024
#define PTS 4   // points per MLP block
#define PX 16   // pixels per splat block (14 x-tiles per row)
#define CH 16   // gaussians per weight chunk (CH*PX == 256 threads)

// ---------------- kernel 1: per-gaussian projection/prep ----------------
__global__ void prep_kernel(const float* __restrict__ gd,
                            const float* __restrict__ Kmat,
                            float4* __restrict__ bbox,
                            float4* __restrict__ prm,
                            int N, int B, float Wf, float Hf) {
  int i = blockIdx.x * blockDim.x + threadIdx.x;
  if (i >= B * N) return;
  int b = i / N;
  const float* g = gd + (size_t)i * 14;
  float X = g[0], Y = g[1], Z = g[2];
  float sigx = g[5], sigy = g[6], wt = g[12];
  const float* K = Kmat + (size_t)b * 9;
  float p0 = K[0]*X + K[1]*Y + K[2]*Z;
  float p1 = K[3]*X + K[4]*Y + K[5]*Z;
  float p2 = K[6]*X + K[7]*Y + K[8]*Z;
  float denom = p2 + 1e-6f;
  float p2x = p0 / denom, p2y = p1 / denom;
  float scale_x = Wf / K[2] * 0.5f;   // W / K[0,2] / 2
  float scale_y = Hf / K[5] * 0.5f;   // H / K[1,2] / 2
  float cx = p2x * scale_x;
  float cy = p2y * scale_y;
  bool valid = Z > 0.1f;
  bool inb = (cx >= 0.f) && (cx < Wf) && (cy >= 0.f) && (cy < Hf);
  bool active = valid && inb;
  float sxv = fmaxf(sigx * scale_x, 1.f);
  float syv = fmaxf(sigy * scale_y, 1.f);
  float wn = active ? wt : 0.f;
  float avg = 0.5f * (sxv + syv);
  if (active && wn != 0.f) {
    bbox[i] = make_float4(cx, cy, 3.f * sxv, 3.f * syv);
  } else {
    bbox[i] = make_float4(-1e30f, -1e30f, 0.f, 0.f);  // never culled-in
  }
  prm[i] = make_float4(1.f / sxv, 1.f / syv, wn, avg);
}

// ---------------- kernel 2: MLP h = relu(pf@W1^T+b1)@W2^T+b2 ----------------
__global__ __launch_bounds__(256) void mlp_kernel(
    const float* __restrict__ pf, const float* __restrict__ W1,
    const float* __restrict__ b1, const float* __restrict__ W2,
    const float* __restrict__ b2, float* __restrict__ hout, int npts) {
  const int t = threadIdx.x;            // output channel (C==256)
  const int p0 = blockIdx.x * PTS;
  __shared__ __align__(16) float xs[PTS][256];

  const float4* pf4 = (const float4*)(pf + (size_t)p0 * 256);
  float4* xs4 = (float4*)&xs[0][0];
  #pragma unroll
  for (int i = 0; i < PTS * 64 / 256; ++i) xs4[t + 256 * i] = pf4[t + 256 * i];
  __syncthreads();

  float acc[PTS];
  float bb1 = b1[t];
  #pragma unroll
  for (int p = 0; p < PTS; ++p) acc[p] = bb1;
  const float* w1r = W1 + (size_t)t * 256;
  for (int k = 0; k < 256; k += 4) {
    float4 w = *(const float4*)(w1r + k);
    #pragma unroll
    for (int p = 0; p < PTS; ++p) {
      float4 x = *(const float4*)(&xs[p][k]);
      acc[p] += w.x * x.x + w.y * x.y + w.z * x.z + w.w * x.w;
    }
  }
  __syncthreads();
  #pragma unroll
  for (int p = 0; p < PTS; ++p) xs[p][t] = fmaxf(acc[p], 0.f);
  __syncthreads();

  float acc2[PTS];
  float bb2 = b2[t];
  #pragma unroll
  for (int p = 0; p < PTS; ++p) acc2[p] = bb2;
  const float* w2r = W2 + (size_t)t * 256;
  for (int k = 0; k < 256; k += 4) {
    float4 w = *(const float4*)(w2r + k);
    #pragma unroll
    for (int p = 0; p < PTS; ++p) {
      float4 x = *(const float4*)(&xs[p][k]);
      acc2[p] += w.x * x.x + w.y * x.y + w.z * x.z + w.w * x.w;
    }
  }
  #pragma unroll
  for (int p = 0; p < PTS; ++p)
    if (p0 + p < npts) hout[((size_t)(p0 + p)) * 256 + t] = acc2[p];
}

// ---------------- kernel 2b: per-row y-cull (hoisted out of splat) ----------
// block = (row, b); writes ascending-g list of row-overlapping gaussians.
__global__ __launch_bounds__(256) void rowcull_kernel(
    const float4* __restrict__ bbox, unsigned short* __restrict__ rowlist,
    int* __restrict__ rowcnt, int N, int H, int W) {
  const int t = threadIdx.x;
  const int row = blockIdx.x;
  const int b = blockIdx.y;
  __shared__ int wcnt[4];
  const float rf = (float)row;
  const float wmax = (float)(W - 1);
  const int lane = t & 63, wave = t >> 6;
  const unsigned long long lmask = (1ull << lane) - 1ull;
  const size_t bN = (size_t)b * N;
  unsigned short* rl = rowlist + ((size_t)b * H + row) * N;

  int listlen = 0;
  for (int gb = 0; gb < N; gb += 256) {
    int g = gb + t;
    bool f = false;
    if (g < N) {
      float4 bb = bbox[bN + g];
      f = (bb.y - bb.w <= rf) && (bb.y + bb.w >= rf) &&
          (bb.x + bb.z >= 0.f) && (bb.x - bb.z <= wmax);
    }
    unsigned long long m = __ballot(f);
    if (lane == 0) wcnt[wave] = __popcll(m);
    __syncthreads();
    int pre = 0;
    #pragma unroll
    for (int wv = 0; wv < 4; ++wv) pre += (wv < wave) ? wcnt[wv] : 0;
    int tot = wcnt[0] + wcnt[1] + wcnt[2] + wcnt[3];
    if (f) rl[listlen + pre + __popcll(m & lmask)] = (unsigned short)g;
    __syncthreads();
    listlen += tot;
  }
  if (t == 0) rowcnt[(size_t)b * H + row] = listlen;
}

// ---------------- kernel 3: gather-splat, 16-px tile per block --------------
// x-cull scans only the per-row list (~tens); weights computed ONCE per block
// into LDS (removes round-5's 256x-redundant exp per channel-thread); phase B
// is pure LDS-broadcast reads + FMA.
__global__ __launch_bounds__(256, 4) void splat_kernel(
    const float4* __restrict__ bbox, const float4* __restrict__ prm,
    const float* __restrict__ hfeat,
    const unsigned short* __restrict__ rowlist, const int* __restrict__ rowcnt,
    float* __restrict__ fout, float* __restrict__ unc_out,
    float* __restrict__ dens_out, int N, int C, int H, int W) {
  const int t = threadIdx.x;
  const int b = blockIdx.z;
  const int row = blockIdx.y;
  const int x0 = blockIdx.x * PX;
  const int HW = H * W;

  __shared__ int glist[512];
  __shared__ int wcnt[4];
  __shared__ __align__(16) float wlds[CH][PX];
  __shared__ __align__(16) float invd_s[PX];
  __shared__ float avgs_s[CH];

  const float rf = (float)row;
  const float xlo = (float)x0, xhi = (float)(x0 + PX - 1);
  const int lane = t & 63, wave = t >> 6;
  const unsigned long long lmask = (1ull << lane) - 1ull;
  const size_t bN = (size_t)b * N;
  const int rcnt = rowcnt[(size_t)b * H + row];
  const unsigned short* rl = rowlist + ((size_t)b * H + row) * N;

  // ---- x-cull over the row list (ballot + cross-wave prefix, ascending) ----
  int listlen = 0;
  for (int rb = 0; rb < rcnt; rb += 256) {
    int g = 0;
    bool f = false;
    if (rb + t < rcnt) {
      g = rl[rb + t];
      float4 bb = bbox[bN + g];
      f = (bb.x + bb.z >= xlo) && (bb.x - bb.z <= xhi);
    }
    unsigned long long m = __ballot(f);
    if (lane == 0) wcnt[wave] = __popcll(m);
    __syncthreads();
    int pre = 0;
    #pragma unroll
    for (int wv = 0; wv < 4; ++wv) pre += (wv < wave) ? wcnt[wv] : 0;
    int tot = wcnt[0] + wcnt[1] + wcnt[2] + wcnt[3];
    if (f) glist[listlen + pre + __popcll(m & lmask)] = g;
    __syncthreads();
    listlen += tot;
  }

  float dreg = 0.f, ureg = 0.f;      // running dens/unc (threads 0..PX-1)
  float acc[PX];
  #pragma unroll
  for (int j = 0; j < PX; ++j) acc[j] = 0.f;

  // ---- chunks of CH gaussians: weights once -> LDS, then reuse ----
  for (int cb = 0; cb < listlen; cb += CH) {
    int gc = min(CH, listlen - cb);
    if (t < gc * PX) {
      int gi = t >> 4, j = t & 15;     // PX==16
      int g = glist[cb + gi];
      float4 bb = bbox[bN + g];
      float4 pr = prm[bN + g];
      float dx = (xlo + (float)j - bb.x) * pr.x;
      float dy = (rf - bb.y) * pr.y;
      float q = dx * dx + dy * dy;
      float w = (q < 9.f) ? __expf(-0.5f * q) * pr.z : 0.f;
      wlds[gi][j] = w;
      if (j == 0) avgs_s[gi] = pr.w;
    }
    __syncthreads();
    // dens/unc: threads 0..15, ascending gi (bitwise same order as reference)
    if (t < PX) {
      for (int gi = 0; gi < gc; ++gi) {
        float w = wlds[gi][t];
        dreg += w;
        ureg += w * avgs_s[gi];
      }
    }
    // feature accumulation: thread = channel, LDS-broadcast weights
    for (int gi = 0; gi < gc; ++gi) {
      float hv = hfeat[(bN + glist[cb + gi]) * (size_t)C + t];
      const float4* wr = (const float4*)&wlds[gi][0];
      float4 w0 = wr[0], w1 = wr[1], w2 = wr[2], w3 = wr[3];
      acc[0]  += w0.x * hv; acc[1]  += w0.y * hv; acc[2]  += w0.z * hv; acc[3]  += w0.w * hv;
      acc[4]  += w1.x * hv; acc[5]  += w1.y * hv; acc[6]  += w1.z * hv; acc[7]  += w1.w * hv;
      acc[8]  += w2.x * hv; acc[9]  += w2.y * hv; acc[10] += w2.z * hv; acc[11] += w2.w * hv;
      acc[12] += w3.x * hv; acc[13] += w3.y * hv; acc[14] += w3.z * hv; acc[15] += w3.w * hv;
    }
    __syncthreads();
  }

  // ---- normalize + write ----
  if (t < PX) {
    float dc = fmaxf(dreg, 1e-6f);
    float inv = 1.f / dc;
    invd_s[t] = inv;
    size_t pix = (size_t)b * HW + (size_t)row * W + x0 + t;
    dens_out[pix] = dc;
    unc_out[pix] = ureg * inv;
  }
  __syncthreads();

  float* fo = fout + ((size_t)(b * C + t)) * HW + (size_t)row * W + x0;
  const float4* iv = (const float4*)invd_s;
  float4 i0 = iv[0], i1 = iv[1], i2 = iv[2], i3 = iv[3];
  *(float4*)(fo)      = make_float4(acc[0]*i0.x,  acc[1]*i0.y,  acc[2]*i0.z,  acc[3]*i0.w);
  *(float4*)(fo + 4)  = make_float4(acc[4]*i1.x,  acc[5]*i1.y,  acc[6]*i1.z,  acc[7]*i1.w);
  *(float4*)(fo + 8)  = make_float4(acc[8]*i2.x,  acc[9]*i2.y,  acc[10]*i2.z, acc[11]*i2.w);
  *(float4*)(fo + 12) = make_float4(acc[12]*i3.x, acc[13]*i3.y, acc[14]*i3.z, acc[15]*i3.w);
}

extern "C" void kernel_launch(void* const* d_in, const int* in_sizes, int n_in,
                              void* d_out, int out_size, void* d_ws, size_t ws_size,
                              hipStream_t stream) {
  const float* pf = (const float*)d_in[0];
  const float* gd = (const float*)d_in[1];
  const float* K  = (const float*)d_in[2];
  const float* W1 = (const float*)d_in[3];
  const float* b1 = (const float*)d_in[4];
  const float* W2 = (const float*)d_in[5];
  const float* b2 = (const float*)d_in[6];

  const int B = in_sizes[2] / 9;
  const int N = in_sizes[1] / (B * 14);
  const int C = in_sizes[0] / (B * N);
  const int H = 128, W = 224;

  float4* bbox = (float4*)d_ws;
  float4* prm  = bbox + (size_t)B * N;
  float*  hfe  = (float*)(prm + (size_t)B * N);
  unsigned short* rowlist = (unsigned short*)(hfe + (size_t)B * N * C);
  int* rowcnt = (int*)(rowlist + (size_t)B * H * N);

  float* out      = (float*)d_out;
  float* unc_out  = out + (size_t)B * C * H * W;
  float* dens_out = unc_out + (size_t)B * H * W;

  prep_kernel<<<dim3((B * N + 255) / 256), 256, 0, stream>>>(
      gd, K, bbox, prm, N, B, (float)W, (float)H);
  mlp_kernel<<<dim3((B * N + PTS - 1) / PTS), 256, 0, stream>>>(
      pf, W1, b1, W2, b2, hfe, B * N);
  rowcull_kernel<<<dim3(H, B), 256, 0, stream>>>(
      bbox, rowlist, rowcnt, N, H, W);
  splat_kernel<<<dim3(W / PX, H, B), 256, 0, stream>>>(
      bbox, prm, hfe, rowlist, rowcnt, out, unc_out, dens_out, N, C, H, W);
}

// Round 7
// 79.260 us; speedup vs baseline: 2.1612x; 1.0480x over previous
//
#include <hip/hip_runtime.h>
#include <math.h>

// Shapes (from setup_inputs): B=2, N=512, C=256, H=128, W=224.
#define PTS 4   // points per MLP block
#define PX 16   // pixels per splat block (14 x-tiles per row)
#define CH 16   // gaussians per weight chunk (CH*PX == 256 threads)

// ---------------- kernel 1: per-gaussian projection/prep ----------------
__global__ void prep_kernel(const float* __restrict__ gd,
                            const float* __restrict__ Kmat,
                            float4* __restrict__ bbox,
                            float4* __restrict__ prm,
                            int N, int B, float Wf, float Hf) {
  int i = blockIdx.x * blockDim.x + threadIdx.x;
  if (i >= B * N) return;
  int b = i / N;
  const float* g = gd + (size_t)i * 14;
  float X = g[0], Y = g[1], Z = g[2];
  float sigx = g[5], sigy = g[6], wt = g[12];
  const float* K = Kmat + (size_t)b * 9;
  float p0 = K[0]*X + K[1]*Y + K[2]*Z;
  float p1 = K[3]*X + K[4]*Y + K[5]*Z;
  float p2 = K[6]*X + K[7]*Y + K[8]*Z;
  float denom = p2 + 1e-6f;
  float p2x = p0 / denom, p2y = p1 / denom;
  float scale_x = Wf / K[2] * 0.5f;   // W / K[0,2] / 2
  float scale_y = Hf / K[5] * 0.5f;   // H / K[1,2] / 2
  float cx = p2x * scale_x;
  float cy = p2y * scale_y;
  bool valid = Z > 0.1f;
  bool inb = (cx >= 0.f) && (cx < Wf) && (cy >= 0.f) && (cy < Hf);
  bool active = valid && inb;
  float sxv = fmaxf(sigx * scale_x, 1.f);
  float syv = fmaxf(sigy * scale_y, 1.f);
  float wn = active ? wt : 0.f;
  float avg = 0.5f * (sxv + syv);
  if (active && wn != 0.f) {
    bbox[i] = make_float4(cx, cy, 3.f * sxv, 3.f * syv);
  } else {
    bbox[i] = make_float4(-1e30f, -1e30f, 0.f, 0.f);  // never culled-in
  }
  prm[i] = make_float4(1.f / sxv, 1.f / syv, wn, avg);
}

// ---------------- kernel 2: MLP h = relu(pf@W1^T+b1)@W2^T+b2 ----------------
__global__ __launch_bounds__(256) void mlp_kernel(
    const float* __restrict__ pf, const float* __restrict__ W1,
    const float* __restrict__ b1, const float* __restrict__ W2,
    const float* __restrict__ b2, float* __restrict__ hout, int npts) {
  const int t = threadIdx.x;            // output channel (C==256)
  const int p0 = blockIdx.x * PTS;
  __shared__ __align__(16) float xs[PTS][256];

  const float4* pf4 = (const float4*)(pf + (size_t)p0 * 256);
  float4* xs4 = (float4*)&xs[0][0];
  #pragma unroll
  for (int i = 0; i < PTS * 64 / 256; ++i) xs4[t + 256 * i] = pf4[t + 256 * i];
  __syncthreads();

  float acc[PTS];
  float bb1 = b1[t];
  #pragma unroll
  for (int p = 0; p < PTS; ++p) acc[p] = bb1;
  const float* w1r = W1 + (size_t)t * 256;
  for (int k = 0; k < 256; k += 4) {
    float4 w = *(const float4*)(w1r + k);
    #pragma unroll
    for (int p = 0; p < PTS; ++p) {
      float4 x = *(const float4*)(&xs[p][k]);
      acc[p] += w.x * x.x + w.y * x.y + w.z * x.z + w.w * x.w;
    }
  }
  __syncthreads();
  #pragma unroll
  for (int p = 0; p < PTS; ++p) xs[p][t] = fmaxf(acc[p], 0.f);
  __syncthreads();

  float acc2[PTS];
  float bb2 = b2[t];
  #pragma unroll
  for (int p = 0; p < PTS; ++p) acc2[p] = bb2;
  const float* w2r = W2 + (size_t)t * 256;
  for (int k = 0; k < 256; k += 4) {
    float4 w = *(const float4*)(w2r + k);
    #pragma unroll
    for (int p = 0; p < PTS; ++p) {
      float4 x = *(const float4*)(&xs[p][k]);
      acc2[p] += w.x * x.x + w.y * x.y + w.z * x.z + w.w * x.w;
    }
  }
  #pragma unroll
  for (int p = 0; p < PTS; ++p)
    if (p0 + p < npts) hout[((size_t)(p0 + p)) * 256 + t] = acc2[p];
}

// ---------------- kernel 2b: per-row y-cull (hoisted out of splat) ----------
__global__ __launch_bounds__(256) void rowcull_kernel(
    const float4* __restrict__ bbox, unsigned short* __restrict__ rowlist,
    int* __restrict__ rowcnt, int N, int H, int W) {
  const int t = threadIdx.x;
  const int row = blockIdx.x;
  const int b = blockIdx.y;
  __shared__ int wcnt[4];
  const float rf = (float)row;
  const float wmax = (float)(W - 1);
  const int lane = t & 63, wave = t >> 6;
  const unsigned long long lmask = (1ull << lane) - 1ull;
  const size_t bN = (size_t)b * N;
  unsigned short* rl = rowlist + ((size_t)b * H + row) * N;

  int listlen = 0;
  for (int gb = 0; gb < N; gb += 256) {
    int g = gb + t;
    bool f = false;
    if (g < N) {
      float4 bb = bbox[bN + g];
      f = (bb.y - bb.w <= rf) && (bb.y + bb.w >= rf) &&
          (bb.x + bb.z >= 0.f) && (bb.x - bb.z <= wmax);
    }
    unsigned long long m = __ballot(f);
    if (lane == 0) wcnt[wave] = __popcll(m);
    __syncthreads();
    int pre = 0;
    #pragma unroll
    for (int wv = 0; wv < 4; ++wv) pre += (wv < wave) ? wcnt[wv] : 0;
    int tot = wcnt[0] + wcnt[1] + wcnt[2] + wcnt[3];
    if (f) rl[listlen + pre + __popcll(m & lmask)] = (unsigned short)g;
    __syncthreads();
    listlen += tot;
  }
  if (t == 0) rowcnt[(size_t)b * H + row] = listlen;
}

// ---------------- kernel 3: gather-splat, 16-px tile per block --------------
// v7: batched hv prefetch (16 independent loads in flight vs round-6's serial
// dependent chain), double-buffered wlds -> ONE barrier per chunk, zero-padded
// weight slots (phase B unpredicated), second 8-gaussian half skipped when
// gc<=8 (common cold-tile case).
__global__ __launch_bounds__(256, 4) void splat_kernel(
    const float4* __restrict__ bbox, const float4* __restrict__ prm,
    const float* __restrict__ hfeat,
    const unsigned short* __restrict__ rowlist, const int* __restrict__ rowcnt,
    float* __restrict__ fout, float* __restrict__ unc_out,
    float* __restrict__ dens_out, int N, int C, int H, int W) {
  const int t = threadIdx.x;
  const int b = blockIdx.z;
  const int row = blockIdx.y;
  const int x0 = blockIdx.x * PX;
  const int HW = H * W;

  __shared__ int glist[512];
  __shared__ int wcnt[4];
  __shared__ __align__(16) float wlds[2][CH][PX];
  __shared__ __align__(16) float invd_s[PX];
  __shared__ float avgs_s[2][CH];

  const float rf = (float)row;
  const float xlo = (float)x0, xhi = (float)(x0 + PX - 1);
  const int lane = t & 63, wave = t >> 6;
  const unsigned long long lmask = (1ull << lane) - 1ull;
  const size_t bN = (size_t)b * N;
  const int rcnt = rowcnt[(size_t)b * H + row];
  const unsigned short* rl = rowlist + ((size_t)b * H + row) * N;

  // ---- x-cull over the row list (ballot + cross-wave prefix, ascending) ----
  int listlen = 0;
  for (int rb = 0; rb < rcnt; rb += 256) {
    int g = 0;
    bool f = false;
    if (rb + t < rcnt) {
      g = rl[rb + t];
      float4 bb = bbox[bN + g];
      f = (bb.x + bb.z >= xlo) && (bb.x - bb.z <= xhi);
    }
    unsigned long long m = __ballot(f);
    if (lane == 0) wcnt[wave] = __popcll(m);
    __syncthreads();
    int pre = 0;
    #pragma unroll
    for (int wv = 0; wv < 4; ++wv) pre += (wv < wave) ? wcnt[wv] : 0;
    int tot = wcnt[0] + wcnt[1] + wcnt[2] + wcnt[3];
    if (f) glist[listlen + pre + __popcll(m & lmask)] = g;
    __syncthreads();
    listlen += tot;
  }

  float dreg = 0.f, ureg = 0.f;      // running dens/unc (threads 0..PX-1)
  float acc[PX];
  #pragma unroll
  for (int j = 0; j < PX; ++j) acc[j] = 0.f;

  const int gi_w = t >> 4, j_w = t & 15;   // this thread's weight slot

  // ---- chunks of CH gaussians: one barrier per chunk (double buffer) ----
  const int nchunk = (listlen + CH - 1) / CH;
  for (int c = 0; c < nchunk; ++c) {
    const int cb = c * CH;
    const int buf = c & 1;
    const int gc = min(CH, listlen - cb);

    // batched hv prefetch: up to 16 INDEPENDENT loads in flight
    float hvv[CH];
    #pragma unroll
    for (int gi = 0; gi < CH; ++gi) {
      if (gi < gc) hvv[gi] = hfeat[(bN + glist[cb + gi]) * (size_t)C + t];
      else         hvv[gi] = 0.f;
    }

    // weights: every slot written every chunk (zero pad -> phase B unpredicated)
    {
      float w = 0.f, av = 0.f;
      if (gi_w < gc) {
        int g = glist[cb + gi_w];
        float4 bb = bbox[bN + g];
        float4 pr = prm[bN + g];
        float dx = (xlo + (float)j_w - bb.x) * pr.x;
        float dy = (rf - bb.y) * pr.y;
        float q = dx * dx + dy * dy;
        w = (q < 9.f) ? __expf(-0.5f * q) * pr.z : 0.f;
        av = pr.w;
      }
      wlds[buf][gi_w][j_w] = w;
      if (j_w == 0) avgs_s[buf][gi_w] = av;
    }
    __syncthreads();

    // dens/unc: threads 0..15, ascending gi (deterministic order)
    if (t < PX) {
      for (int gi = 0; gi < gc; ++gi) {
        float w = wlds[buf][gi][t];
        dreg += w;
        ureg += w * avgs_s[buf][gi];
      }
    }

    // feature accumulation: thread = channel, LDS-broadcast weights
    const float4* wr = (const float4*)&wlds[buf][0][0];
    #pragma unroll
    for (int gi = 0; gi < 8; ++gi) {
      float4 w0 = wr[gi*4+0], w1 = wr[gi*4+1], w2 = wr[gi*4+2], w3 = wr[gi*4+3];
      float hv = hvv[gi];
      acc[0]  += w0.x*hv; acc[1]  += w0.y*hv; acc[2]  += w0.z*hv; acc[3]  += w0.w*hv;
      acc[4]  += w1.x*hv; acc[5]  += w1.y*hv; acc[6]  += w1.z*hv; acc[7]  += w1.w*hv;
      acc[8]  += w2.x*hv; acc[9]  += w2.y*hv; acc[10] += w2.z*hv; acc[11] += w2.w*hv;
      acc[12] += w3.x*hv; acc[13] += w3.y*hv; acc[14] += w3.z*hv; acc[15] += w3.w*hv;
    }
    if (gc > 8) {
      #pragma unroll
      for (int gi = 8; gi < CH; ++gi) {
        float4 w0 = wr[gi*4+0], w1 = wr[gi*4+1], w2 = wr[gi*4+2], w3 = wr[gi*4+3];
        float hv = hvv[gi];
        acc[0]  += w0.x*hv; acc[1]  += w0.y*hv; acc[2]  += w0.z*hv; acc[3]  += w0.w*hv;
        acc[4]  += w1.x*hv; acc[5]  += w1.y*hv; acc[6]  += w1.z*hv; acc[7]  += w1.w*hv;
        acc[8]  += w2.x*hv; acc[9]  += w2.y*hv; acc[10] += w2.z*hv; acc[11] += w2.w*hv;
        acc[12] += w3.x*hv; acc[13] += w3.y*hv; acc[14] += w3.z*hv; acc[15] += w3.w*hv;
      }
    }
    // no trailing barrier: next chunk writes the OTHER wlds buffer
  }

  // ---- normalize + write ----
  if (t < PX) {
    float dc = fmaxf(dreg, 1e-6f);
    float inv = 1.f / dc;
    invd_s[t] = inv;
    size_t pix = (size_t)b * HW + (size_t)row * W + x0 + t;
    dens_out[pix] = dc;
    unc_out[pix] = ureg * inv;
  }
  __syncthreads();

  float* fo = fout + ((size_t)(b * C + t)) * HW + (size_t)row * W + x0;
  const float4* iv = (const float4*)invd_s;
  float4 i0 = iv[0], i1 = iv[1], i2 = iv[2], i3 = iv[3];
  *(float4*)(fo)      = make_float4(acc[0]*i0.x,  acc[1]*i0.y,  acc[2]*i0.z,  acc[3]*i0.w);
  *(float4*)(fo + 4)  = make_float4(acc[4]*i1.x,  acc[5]*i1.y,  acc[6]*i1.z,  acc[7]*i1.w);
  *(float4*)(fo + 8)  = make_float4(acc[8]*i2.x,  acc[9]*i2.y,  acc[10]*i2.z, acc[11]*i2.w);
  *(float4*)(fo + 12) = make_float4(acc[12]*i3.x, acc[13]*i3.y, acc[14]*i3.z, acc[15]*i3.w);
}

extern "C" void kernel_launch(void* const* d_in, const int* in_sizes, int n_in,
                              void* d_out, int out_size, void* d_ws, size_t ws_size,
                              hipStream_t stream) {
  const float* pf = (const float*)d_in[0];
  const float* gd = (const float*)d_in[1];
  const float* K  = (const float*)d_in[2];
  const float* W1 = (const float*)d_in[3];
  const float* b1 = (const float*)d_in[4];
  const float* W2 = (const float*)d_in[5];
  const float* b2 = (const float*)d_in[6];

  const int B = in_sizes[2] / 9;
  const int N = in_sizes[1] / (B * 14);
  const int C = in_sizes[0] / (B * N);
  const int H = 128, W = 224;

  float4* bbox = (float4*)d_ws;
  float4* prm  = bbox + (size_t)B * N;
  float*  hfe  = (float*)(prm + (size_t)B * N);
  unsigned short* rowlist = (unsigned short*)(hfe + (size_t)B * N * C);
  int* rowcnt = (int*)(rowlist + (size_t)B * H * N);

  float* out      = (float*)d_out;
  float* unc_out  = out + (size_t)B * C * H * W;
  float* dens_out = unc_out + (size_t)B * H * W;

  prep_kernel<<<dim3((B * N + 255) / 256), 256, 0, stream>>>(
      gd, K, bbox, prm, N, B, (float)W, (float)H);
  mlp_kernel<<<dim3((B * N + PTS - 1) / PTS), 256, 0, stream>>>(
      pf, W1, b1, W2, b2, hfe, B * N);
  rowcull_kernel<<<dim3(H, B), 256, 0, stream>>>(
      bbox, rowlist, rowcnt, N, H, W);
  splat_kernel<<<dim3(W / PX, H, B), 256, 0, stream>>>(
      bbox, prm, hfe, rowlist, rowcnt, out, unc_out, dens_out, N, C, H, W);
}